// Round 3
// baseline (636.593 us; speedup 1.0000x reference)
//
#include <hip/hip_runtime.h>

typedef float f32x4 __attribute__((ext_vector_type(4)));
typedef short bf16x8 __attribute__((ext_vector_type(8)));

#define BATCH 131072
#define SEQT  20

// ---------- fast activations ----------
__device__ __forceinline__ float fexp2(float x){ return __builtin_amdgcn_exp2f(x); }
__device__ __forceinline__ float frcp (float x){ return __builtin_amdgcn_rcpf(x); }

// ---------- bf16 helpers (RNE) ----------
__device__ __forceinline__ unsigned short f2bf(float f){
  unsigned u = __float_as_uint(f);
  return (unsigned short)((u + 0x7fffu + ((u>>16)&1u)) >> 16);
}
__device__ __forceinline__ float bf2f(unsigned short b){ return __uint_as_float(((unsigned)b)<<16); }
__device__ __forceinline__ unsigned pk2(float a, float b){ return (unsigned)f2bf(a) | ((unsigned)f2bf(b)<<16); }

__device__ __forceinline__ f32x4 MFMA(bf16x8 a, bf16x8 b, f32x4 c){
  return __builtin_amdgcn_mfma_f32_16x16x32_bf16(a, b, c, 0, 0, 0);
}
__device__ __forceinline__ bf16x8 zero8(){
  bf16x8 z;
#pragma unroll
  for (int e=0;e<8;++e) z[e]=0;
  return z;
}

// sigma column permutation: B-frag element e at lane-group kg holds hidden j = (e>>2)*16 + 4*kg + (e&3)
__device__ __forceinline__ int sigcol(int kg, int e){ return (e<4) ? (4*kg+e) : (16+4*kg+(e-4)); }

// A-frag loaders (row = global row of W; lane holds 8 K-elements)
__device__ __forceinline__ bf16x8 ldfragS(const float* __restrict__ W, int row, int kg){ // K=32, sigma cols
  bf16x8 f;
#pragma unroll
  for (int e=0;e<8;++e) f[e] = (short)f2bf(W[row*32 + sigcol(kg,e)]);
  return f;
}
__device__ __forceinline__ bf16x8 ldfragX(const float* __restrict__ W, int row, int kg){ // K=5 natural, zero-pad to 32
  bf16x8 f;
#pragma unroll
  for (int e=0;e<8;++e){
    f[e] = (short)((kg==0 && e<5) ? f2bf(W[row*5 + e]) : (short)0);
  }
  return f;
}
__device__ __forceinline__ bf16x8 ldfragE(const float* __restrict__ W, int row, int kg){ // K=16 (latent), sigma2: col=4kg+e for e<4
  bf16x8 f;
#pragma unroll
  for (int e=0;e<8;++e) f[e] = (short)((e<4) ? f2bf(W[row*16 + 4*kg + e]) : (short)0);
  return f;
}

// ---------- gate nonlinearity + state update + sigma-pack ----------
// Fused-rcp forms:  sig(a)*tanh(b) = (B-1)/((1+A)(B+1)), A=2^(-a*L), B=2^(2b*L)
// 8 quarter-rate trans instrs per gate-quad instead of 10.
__device__ __forceinline__ void activate(const f32x4* acc, float* cs, bf16x8& ph, bf16x8& phr){
  const float L1 = 1.4426950408889634f;
#pragma unroll
  for (int mm=0; mm<2; ++mm)
#pragma unroll
  for (int r=0; r<4; ++r){
    float zi = acc[0+mm][r];
    float zf = acc[2+mm][r];
    float zg = acc[4+mm][r];
    float zo = acc[6+mm][r];
    // ig = sigm(zi)*tanh(zg)
    float A  = fexp2(-L1*zi);
    float B  = fexp2(2.0f*L1*zg);
    float ig = (B-1.0f)*frcp((1.0f+A)*(B+1.0f));
    // fg = sigm(zf)
    float fg = frcp(1.0f + fexp2(-L1*zf));
    const int e = mm*4 + r;
    float cn = fmaf(fg, cs[e], ig);
    cs[e] = cn;
    // h = sigm(zo)*tanh(cn)
    float E  = fexp2(-L1*zo);
    float D  = fexp2(2.0f*L1*cn);
    float h  = (D-1.0f)*frcp((1.0f+E)*(D+1.0f));
    unsigned short hb = f2bf(h);
    ph[e]  = (short)hb;
    phr[e] = (short)f2bf(h - bf2f(hb));
  }
}

__global__ __launch_bounds__(256) void lstm_ae_mfma(
    const float* __restrict__ x,
    const float* __restrict__ eWih0, const float* __restrict__ eWhh0,
    const float* __restrict__ ebih0, const float* __restrict__ ebhh0,
    const float* __restrict__ eWih1, const float* __restrict__ eWhh1,
    const float* __restrict__ ebih1, const float* __restrict__ ebhh1,
    const float* __restrict__ bnW,   const float* __restrict__ bnB,
    const float* __restrict__ exW,   const float* __restrict__ exB,
    const float* __restrict__ dWih0, const float* __restrict__ dWhh0,
    const float* __restrict__ dbih0, const float* __restrict__ dbhh0,
    const float* __restrict__ dWih1, const float* __restrict__ dWhh1,
    const float* __restrict__ dbih1, const float* __restrict__ dbhh1,
    const float* __restrict__ outW,  const float* __restrict__ outB,
    float* __restrict__ out)
{
  const int tid  = threadIdx.x;
  const int lane = tid & 63;
  const int w    = tid >> 6;      // wave id (0..3)
  const int cl   = lane & 15;     // batch col within wave / row-in-tile for A frags
  const int kg   = lane >> 4;     // k-group (0..3)

  // LDS: biases (576 f32) + x-frags (4 waves x 20 t x 16 col x 16B) + zero slot + out staging
  __shared__ __align__(16) float    sb[576];
  __shared__ __align__(16) unsigned sx[5124];
  __shared__ __align__(16) float    sout[6400];

  // ---- bias prep (bih+bhh summed) ----
  if (tid < 128){
    sb[      tid] = ebih0[tid] + ebhh0[tid];
    sb[128 + tid] = ebih1[tid] + ebhh1[tid];
    sb[256 + tid] = dbih0[tid] + dbhh0[tid];
    sb[384 + tid] = dbih1[tid] + dbhh1[tid];
  }
  if (tid < 16){
    sb[512 + tid] = (tid < 5) ? outB[tid] : 0.0f;
    sb[528 + tid] = bnB[tid];
  }
  if (tid < 32) sb[544 + tid] = exB[tid];
  if (tid < 4)  sx[5120 + tid] = 0u;

  // ---- x staging into B-frag layout (bf16, features at k=0..4, rest zero) ----
  const long blockb = (long)blockIdx.x * 64;
#pragma unroll
  for (int q=0; q<5; ++q){
    int s  = tid*5 + q;          // 0..1279 == (bb, t)
    int bb = s / 20;
    int t  = s - bb*20;
    const float* xp = x + (blockb + bb)*100 + t*5;
    float v0=xp[0], v1=xp[1], v2=xp[2], v3=xp[3], v4=xp[4];
    int base = (((bb>>4)*20 + t)*16 + (bb&15))*4;
    sx[base+0] = pk2(v0,v1);
    sx[base+1] = pk2(v2,v3);
    sx[base+2] = pk2(v4,0.0f);
    sx[base+3] = 0u;
  }
  __syncthreads();

  // ---- encoder weight fragments in registers ----
  bf16x8 WA[8], WB[8], WC[8], WD[8];   // Whh0, Wih0(x), Wih1, Whh1
#pragma unroll
  for (int m=0; m<8; ++m){
    WA[m] = ldfragS(eWhh0, m*16+cl, kg);
    WB[m] = ldfragX(eWih0, m*16+cl, kg);
    WC[m] = ldfragS(eWih1, m*16+cl, kg);
    WD[m] = ldfragS(eWhh1, m*16+cl, kg);
  }

  f32x4 acc[8];
  float cs0[8], cs1[8];
#pragma unroll
  for (int e=0;e<8;++e){ cs0[e]=0.f; cs1[e]=0.f; }
  bf16x8 ph0 = zero8(), ph0r = zero8(), ph1 = zero8(), ph1r = zero8();

  const unsigned xbase   = (kg==0) ? (unsigned)(w*1280 + cl*4) : 5120u;
  const unsigned xstride = (kg==0) ? 64u : 0u;

  // ================= encoder =================
  for (int t=0; t<SEQT; ++t){
    // enc layer 0: acc = bias0 + Whh0@(h0+res) + Wih0@x
#pragma unroll
    for (int m=0; m<8; ++m){
      f32x4 b = *(const f32x4*)&sb[0 + m*16 + kg*4];
      b = MFMA(WA[m], ph0r, b);
      b = MFMA(WA[m], ph0 , b);
      acc[m] = b;
    }
    bf16x8 xf = *(const bf16x8*)&sx[xbase + t*xstride];
#pragma unroll
    for (int m=0; m<8; ++m) acc[m] = MFMA(WB[m], xf, acc[m]);
    activate(acc, cs0, ph0, ph0r);

    // enc layer 1: acc = bias1 + Whh1@(h1+res) + Wih1@(h0+res)
#pragma unroll
    for (int m=0; m<8; ++m){
      f32x4 b = *(const f32x4*)&sb[128 + m*16 + kg*4];
      b = MFMA(WD[m], ph1r, b);
      b = MFMA(WD[m], ph1 , b);
      b = MFMA(WC[m], ph0r, b);
      b = MFMA(WC[m], ph0 , b);
      acc[m] = b;
    }
    activate(acc, cs1, ph1, ph1r);
  }

  // ================= bottleneck =================
  // latent = relu(bnW @ h1 + bnB): one 16x16 tile
  {
    bf16x8 WBN = ldfragS(bnW, cl, kg);
    f32x4 aL = *(const f32x4*)&sb[528 + kg*4];
    aL = MFMA(WBN, ph1r, aL);
    aL = MFMA(WBN, ph1 , aL);
    bf16x8 ltf = zero8(), ltr = zero8();
#pragma unroll
    for (int r=0; r<4; ++r){
      float v = fmaxf(aL[r], 0.0f);
      unsigned short hb = f2bf(v);
      ltf[r] = (short)hb;
      ltr[r] = (short)f2bf(v - bf2f(hb));
    }
    // ex = relu(exW @ latent + exB): two tiles (rows 0..31), K=16 (sigma2)
    f32x4 aE[2];
#pragma unroll
    for (int m=0; m<2; ++m){
      bf16x8 WE = ldfragE(exW, m*16+cl, kg);
      f32x4 b = *(const f32x4*)&sb[544 + m*16 + kg*4];
      b = MFMA(WE, ltr, b);
      b = MFMA(WE, ltf, b);
      aE[m] = b;
    }
    bf16x8 exf = zero8(), exr = zero8();
#pragma unroll
    for (int e=0; e<8; ++e){
      float v = fmaxf(aE[e>>2][e&3], 0.0f);
      unsigned short hb = f2bf(v);
      exf[e] = (short)hb;
      exr[e] = (short)f2bf(v - bf2f(hb));
    }
    // dec0 constant pre-activation: dpre = dbias0 + dWih0 @ ex  (held in regs)
#pragma unroll
    for (int m=0; m<8; ++m){
      bf16x8 wm = ldfragS(dWih0, m*16+cl, kg);
      f32x4 b = *(const f32x4*)&sb[256 + m*16 + kg*4];
      b = MFMA(wm, exr, b);
      b = MFMA(wm, exf, b);
      acc[m] = b;            // temporarily park dpre in acc
    }
  }
  f32x4 dpre[8];
#pragma unroll
  for (int m=0; m<8; ++m) dpre[m] = acc[m];

  // ---- decoder weights (reuse register arrays) ----
#pragma unroll
  for (int m=0; m<8; ++m){
    WA[m] = ldfragS(dWhh0, m*16+cl, kg);
    WC[m] = ldfragS(dWih1, m*16+cl, kg);
    WD[m] = ldfragS(dWhh1, m*16+cl, kg);
  }
  bf16x8 WO = zero8();
  if (cl < 5) WO = ldfragS(outW, cl, kg);
  const f32x4 obias = *(const f32x4*)&sb[512 + kg*4];

  // reset state
#pragma unroll
  for (int e=0;e<8;++e){ cs0[e]=0.f; cs1[e]=0.f; }
  ph0 = zero8(); ph0r = zero8(); ph1 = zero8(); ph1r = zero8();

  const int obase = w*1600 + cl*100;

  // ================= decoder =================
  for (int t=0; t<SEQT; ++t){
    // dec layer 0: acc = dpre + Whh0d@(h0+res)
#pragma unroll
    for (int m=0; m<8; ++m){
      f32x4 b = dpre[m];
      b = MFMA(WA[m], ph0r, b);
      b = MFMA(WA[m], ph0 , b);
      acc[m] = b;
    }
    activate(acc, cs0, ph0, ph0r);

    // dec layer 1
#pragma unroll
    for (int m=0; m<8; ++m){
      f32x4 b = *(const f32x4*)&sb[384 + m*16 + kg*4];
      b = MFMA(WD[m], ph1r, b);
      b = MFMA(WD[m], ph1 , b);
      b = MFMA(WC[m], ph0r, b);
      b = MFMA(WC[m], ph0 , b);
      acc[m] = b;
    }
    activate(acc, cs1, ph1, ph1r);

    // output projection (one padded tile, rows 0..4 live)
    f32x4 o = obias;
    o = MFMA(WO, ph1r, o);
    o = MFMA(WO, ph1 , o);
#pragma unroll
    for (int r=0; r<4; ++r){
      int f = 4*kg + r;
      if (f < 5) sout[obase + t*5 + f] = o[r];
    }
  }

  // ---- coalesced flush of staged outputs ----
  __syncthreads();
  float* __restrict__ ob = out + blockb*100;
#pragma unroll
  for (int q=0; q<25; ++q) ob[q*256 + tid] = sout[q*256 + tid];
}

extern "C" void kernel_launch(void* const* d_in, const int* in_sizes, int n_in,
                              void* d_out, int out_size, void* d_ws, size_t ws_size,
                              hipStream_t stream)
{
  const float* x     = (const float*)d_in[0];
  const float* eWih0 = (const float*)d_in[1];
  const float* eWhh0 = (const float*)d_in[2];
  const float* ebih0 = (const float*)d_in[3];
  const float* ebhh0 = (const float*)d_in[4];
  const float* eWih1 = (const float*)d_in[5];
  const float* eWhh1 = (const float*)d_in[6];
  const float* ebih1 = (const float*)d_in[7];
  const float* ebhh1 = (const float*)d_in[8];
  const float* bnW   = (const float*)d_in[9];
  const float* bnB   = (const float*)d_in[10];
  const float* exW   = (const float*)d_in[11];
  const float* exB   = (const float*)d_in[12];
  const float* dWih0 = (const float*)d_in[13];
  const float* dWhh0 = (const float*)d_in[14];
  const float* dbih0 = (const float*)d_in[15];
  const float* dbhh0 = (const float*)d_in[16];
  const float* dWih1 = (const float*)d_in[17];
  const float* dWhh1 = (const float*)d_in[18];
  const float* dbih1 = (const float*)d_in[19];
  const float* dbhh1 = (const float*)d_in[20];
  const float* outW  = (const float*)d_in[21];
  const float* outB  = (const float*)d_in[22];

  dim3 grid(BATCH / 64), block(256);
  hipLaunchKernelGGL(lstm_ae_mfma, grid, block, 0, stream,
                     x,
                     eWih0, eWhh0, ebih0, ebhh0,
                     eWih1, eWhh1, ebih1, ebhh1,
                     bnW, bnB, exW, exB,
                     dWih0, dWhh0, dbih0, dbhh0,
                     dWih1, dWhh1, dbih1, dbhh1,
                     outW, outB,
                     (float*)d_out);
}

// Round 4
// 450.863 us; speedup vs baseline: 1.4119x; 1.4119x over previous
//
#include <hip/hip_runtime.h>

typedef float f32x4 __attribute__((ext_vector_type(4)));
typedef short bf16x8 __attribute__((ext_vector_type(8)));

#define BATCH 131072
#define SEQT  20

// ---------- fast activations ----------
__device__ __forceinline__ float fexp2(float x){ return __builtin_amdgcn_exp2f(x); }
__device__ __forceinline__ float frcp (float x){ return __builtin_amdgcn_rcpf(x); }

// ---------- bf16 helpers (RNE) ----------
__device__ __forceinline__ unsigned short f2bf(float f){
  unsigned u = __float_as_uint(f);
  return (unsigned short)((u + 0x7fffu + ((u>>16)&1u)) >> 16);
}
__device__ __forceinline__ float bf2f(unsigned short b){ return __uint_as_float(((unsigned)b)<<16); }
__device__ __forceinline__ unsigned pk2(float a, float b){ return (unsigned)f2bf(a) | ((unsigned)f2bf(b)<<16); }

__device__ __forceinline__ f32x4 MFMA(bf16x8 a, bf16x8 b, f32x4 c){
  return __builtin_amdgcn_mfma_f32_16x16x32_bf16(a, b, c, 0, 0, 0);
}
__device__ __forceinline__ bf16x8 zero8(){
  bf16x8 z;
#pragma unroll
  for (int e=0;e<8;++e) z[e]=0;
  return z;
}

// sigma column permutation: B-frag element e at lane-group kg holds hidden j = (e>>2)*16 + 4*kg + (e&3)
__device__ __forceinline__ int sigcol(int kg, int e){ return (e<4) ? (4*kg+e) : (16+4*kg+(e-4)); }

// A-frag builders from global f32 weights (used for LDS staging + bottleneck)
__device__ __forceinline__ bf16x8 ldfragS(const float* __restrict__ W, int row, int kg){ // K=32, sigma cols
  bf16x8 f;
#pragma unroll
  for (int e=0;e<8;++e) f[e] = (short)f2bf(W[row*32 + sigcol(kg,e)]);
  return f;
}
__device__ __forceinline__ bf16x8 ldfragE(const float* __restrict__ W, int row, int kg){ // K=16 (latent), col=4kg+e for e<4
  bf16x8 f;
#pragma unroll
  for (int e=0;e<8;++e) f[e] = (short)((e<4) ? f2bf(W[row*16 + 4*kg + e]) : (short)0);
  return f;
}

// ---------- gate nonlinearity + state update + sigma-pack ----------
__device__ __forceinline__ void activate(const f32x4* acc, float* cs, bf16x8& ph, bf16x8& phr){
  const float L1 = 1.4426950408889634f;
#pragma unroll
  for (int mm=0; mm<2; ++mm)
#pragma unroll
  for (int r=0; r<4; ++r){
    float zi = acc[0+mm][r];
    float zf = acc[2+mm][r];
    float zg = acc[4+mm][r];
    float zo = acc[6+mm][r];
    float A  = fexp2(-L1*zi);
    float B  = fexp2(2.0f*L1*zg);
    float ig = (B-1.0f)*frcp((1.0f+A)*(B+1.0f));   // sigm(zi)*tanh(zg)
    float fg = frcp(1.0f + fexp2(-L1*zf));
    const int e = mm*4 + r;
    float cn = fmaf(fg, cs[e], ig);
    cs[e] = cn;
    float E  = fexp2(-L1*zo);
    float D  = fexp2(2.0f*L1*cn);
    float h  = (D-1.0f)*frcp((1.0f+E)*(D+1.0f));   // sigm(zo)*tanh(cn)
    unsigned short hb = f2bf(h);
    ph[e]  = (short)hb;
    phr[e] = (short)f2bf(h - bf2f(hb));
  }
}

__global__ __launch_bounds__(256, 3) void lstm_ae_mfma(
    const float* __restrict__ x,
    const float* __restrict__ eWih0, const float* __restrict__ eWhh0,
    const float* __restrict__ ebih0, const float* __restrict__ ebhh0,
    const float* __restrict__ eWih1, const float* __restrict__ eWhh1,
    const float* __restrict__ ebih1, const float* __restrict__ ebhh1,
    const float* __restrict__ bnW,   const float* __restrict__ bnB,
    const float* __restrict__ exW,   const float* __restrict__ exB,
    const float* __restrict__ dWih0, const float* __restrict__ dWhh0,
    const float* __restrict__ dbih0, const float* __restrict__ dbhh0,
    const float* __restrict__ dWih1, const float* __restrict__ dWhh1,
    const float* __restrict__ dbih1, const float* __restrict__ dbhh1,
    const float* __restrict__ outW,  const float* __restrict__ outB,
    float* __restrict__ out)
{
  const int tid  = threadIdx.x;
  const int lane = tid & 63;
  const int w    = tid >> 6;      // wave id (0..3)
  const int cl   = lane & 15;     // batch col within wave / A-frag row
  const int kg   = lane >> 4;     // k-group (0..3)

  // LDS: biases + x-staging (+zero slot) + weight-fragment region (enc/dec shared)
  __shared__ __align__(16) float          sb[576];
  __shared__ __align__(16) unsigned       sx[5124];
  __shared__ __align__(16) unsigned short sfrag[13312];   // 1664 frags x 16B = 26.6 KB

  // ---- bias prep (bih+bhh summed) ----
  if (tid < 128){
    sb[      tid] = ebih0[tid] + ebhh0[tid];
    sb[128 + tid] = ebih1[tid] + ebhh1[tid];
    sb[256 + tid] = dbih0[tid] + dbhh0[tid];
    sb[384 + tid] = dbih1[tid] + dbhh1[tid];
  }
  if (tid < 16){
    sb[512 + tid] = (tid < 5) ? outB[tid] : 0.0f;
    sb[528 + tid] = bnB[tid];
  }
  if (tid < 32) sb[544 + tid] = exB[tid];
  if (tid < 4)  sx[5120 + tid] = 0u;

  // ---- x staging into B-frag layout ----
  const long blockb = (long)blockIdx.x * 64;
#pragma unroll
  for (int q=0; q<5; ++q){
    int s  = tid*5 + q;          // (bb, t)
    int bb = s / 20;
    int t  = s - bb*20;
    const float* xp = x + (blockb + bb)*100 + t*5;
    float v0=xp[0], v1=xp[1], v2=xp[2], v3=xp[3], v4=xp[4];
    int base = (((bb>>4)*20 + t)*16 + (bb&15))*4;
    sx[base+0] = pk2(v0,v1);
    sx[base+1] = pk2(v2,v3);
    sx[base+2] = pk2(v4,0.0f);
    sx[base+3] = 0u;
  }

  // ---- stage ENCODER weight frags into LDS ----
  // layout (frag units of 16B): [0]=Whh0 (8m x 64lane), [512]=Wih1, [1024]=Whh1, [1536]=Wih0 (8m x 16cl)
#pragma unroll
  for (int q=0; q<6; ++q){
    int tile = w + 4*q;                 // 0..23
    int mat  = tile >> 3, m = tile & 7;
    const float* Wm = (mat==0) ? eWhh0 : (mat==1) ? eWih1 : eWhh1;
    bf16x8 f = ldfragS(Wm, m*16+cl, kg);
    *(bf16x8*)&sfrag[(mat*512 + m*64 + lane)*8] = f;
  }
  if (tid < 128){
    int m = tid >> 4, r = tid & 15;
    bf16x8 f;
#pragma unroll
    for (int e=0;e<8;++e) f[e] = (short)((e<5) ? f2bf(eWih0[(m*16+r)*5+e]) : (short)0);
    *(bf16x8*)&sfrag[(1536 + m*16 + r)*8] = f;
  }
  __syncthreads();

  f32x4 acc[8];
  float cs0[8], cs1[8];
#pragma unroll
  for (int e=0;e<8;++e){ cs0[e]=0.f; cs1[e]=0.f; }
  bf16x8 ph0 = zero8(), ph0r = zero8(), ph1 = zero8(), ph1r = zero8();

  const unsigned xbase   = (kg==0) ? (unsigned)(w*1280 + cl*4) : 5120u;
  const unsigned xstride = (kg==0) ? 64u : 0u;
  // Wih0 frag address: kg==0 lanes real, others the 16B zero slot
  const unsigned short* wih0p = (kg==0) ? &sfrag[(1536 + cl)*8] : (const unsigned short*)&sx[5120];
  const unsigned wih0s = (kg==0) ? 128u : 0u;   // stride per m in shorts (16 frags * 8)

  // ================= encoder =================
  for (int t=0; t<SEQT; ++t){
    asm volatile("" ::: "memory");     // keep LDS frag reads inside the loop
    // enc layer 0
#pragma unroll
    for (int m=0; m<8; ++m){
      bf16x8 fa = *(const bf16x8*)&sfrag[(m*64 + lane)*8];
      f32x4 b = *(const f32x4*)&sb[0 + m*16 + kg*4];
      b = MFMA(fa, ph0r, b);
      b = MFMA(fa, ph0 , b);
      acc[m] = b;
    }
    bf16x8 xf = *(const bf16x8*)&sx[xbase + t*xstride];
#pragma unroll
    for (int m=0; m<8; ++m){
      bf16x8 fb = *(const bf16x8*)&wih0p[m*wih0s];
      acc[m] = MFMA(fb, xf, acc[m]);
    }
    activate(acc, cs0, ph0, ph0r);

    // enc layer 1
#pragma unroll
    for (int m=0; m<8; ++m){
      bf16x8 fd = *(const bf16x8*)&sfrag[(1024 + m*64 + lane)*8];
      bf16x8 fc = *(const bf16x8*)&sfrag[( 512 + m*64 + lane)*8];
      f32x4 b = *(const f32x4*)&sb[128 + m*16 + kg*4];
      b = MFMA(fd, ph1r, b);
      b = MFMA(fd, ph1 , b);
      b = MFMA(fc, ph0r, b);
      b = MFMA(fc, ph0 , b);
      acc[m] = b;
    }
    activate(acc, cs1, ph1, ph1r);
  }
  __syncthreads();   // all waves done with enc frags & sx

  // ---- stage DECODER weight frags (overwrites enc region) ----
#pragma unroll
  for (int q=0; q<6; ++q){
    int tile = w + 4*q;
    int mat  = tile >> 3, m = tile & 7;
    const float* Wm = (mat==0) ? dWhh0 : (mat==1) ? dWih1 : dWhh1;
    bf16x8 f = ldfragS(Wm, m*16+cl, kg);
    *(bf16x8*)&sfrag[(mat*512 + m*64 + lane)*8] = f;
  }
  if (tid < 64){
    int r2 = tid & 15, k2 = tid >> 4;
    bf16x8 f = (r2 < 5) ? ldfragS(outW, r2, k2) : zero8();
    *(bf16x8*)&sfrag[(1536 + tid)*8] = f;
  }

  // ---- bottleneck (registers + global weight reads only) ----
  f32x4 dpre[8];
  {
    bf16x8 WBN = ldfragS(bnW, cl, kg);
    f32x4 aL = *(const f32x4*)&sb[528 + kg*4];
    aL = MFMA(WBN, ph1r, aL);
    aL = MFMA(WBN, ph1 , aL);
    bf16x8 ltf = zero8(), ltr = zero8();
#pragma unroll
    for (int r=0; r<4; ++r){
      float v = fmaxf(aL[r], 0.0f);
      unsigned short hb = f2bf(v);
      ltf[r] = (short)hb;
      ltr[r] = (short)f2bf(v - bf2f(hb));
    }
    f32x4 aE[2];
#pragma unroll
    for (int m=0; m<2; ++m){
      bf16x8 WE = ldfragE(exW, m*16+cl, kg);
      f32x4 b = *(const f32x4*)&sb[544 + m*16 + kg*4];
      b = MFMA(WE, ltr, b);
      b = MFMA(WE, ltf, b);
      aE[m] = b;
    }
    bf16x8 exf = zero8(), exr = zero8();
#pragma unroll
    for (int e=0; e<8; ++e){
      float v = fmaxf(aE[e>>2][e&3], 0.0f);
      unsigned short hb = f2bf(v);
      exf[e] = (short)hb;
      exr[e] = (short)f2bf(v - bf2f(hb));
    }
#pragma unroll
    for (int m=0; m<8; ++m){
      bf16x8 wm = ldfragS(dWih0, m*16+cl, kg);
      f32x4 b = *(const f32x4*)&sb[256 + m*16 + kg*4];
      b = MFMA(wm, exr, b);
      b = MFMA(wm, exf, b);
      dpre[m] = b;
    }
  }

  // reset state
#pragma unroll
  for (int e=0;e<8;++e){ cs0[e]=0.f; cs1[e]=0.f; }
  ph0 = zero8(); ph0r = zero8(); ph1 = zero8(); ph1r = zero8();

  __syncthreads();   // dec frags staged

  const f32x4 obias = *(const f32x4*)&sb[512 + kg*4];
  float* __restrict__ obp = out + (blockb + w*16 + cl)*100;

  // ================= decoder =================
  for (int t=0; t<SEQT; ++t){
    asm volatile("" ::: "memory");
    // dec layer 0: acc = dpre + Whh0d@(h0+res)
#pragma unroll
    for (int m=0; m<8; ++m){
      bf16x8 fa = *(const bf16x8*)&sfrag[(m*64 + lane)*8];
      f32x4 b = dpre[m];
      b = MFMA(fa, ph0r, b);
      b = MFMA(fa, ph0 , b);
      acc[m] = b;
    }
    activate(acc, cs0, ph0, ph0r);

    // dec layer 1
#pragma unroll
    for (int m=0; m<8; ++m){
      bf16x8 fd = *(const bf16x8*)&sfrag[(1024 + m*64 + lane)*8];
      bf16x8 fc = *(const bf16x8*)&sfrag[( 512 + m*64 + lane)*8];
      f32x4 b = *(const f32x4*)&sb[384 + m*16 + kg*4];
      b = MFMA(fd, ph1r, b);
      b = MFMA(fd, ph1 , b);
      b = MFMA(fc, ph0r, b);
      b = MFMA(fc, ph0 , b);
      acc[m] = b;
    }
    activate(acc, cs1, ph1, ph1r);

    // output projection
    bf16x8 fo = *(const bf16x8*)&sfrag[(1536 + lane)*8];
    f32x4 o = obias;
    o = MFMA(fo, ph1r, o);
    o = MFMA(fo, ph1 , o);
    float* op = obp + t*5;
    if (kg == 0){
      op[0] = o[0]; op[1] = o[1]; op[2] = o[2]; op[3] = o[3];
    } else if (kg == 1){
      op[4] = o[0];
    }
  }
}

extern "C" void kernel_launch(void* const* d_in, const int* in_sizes, int n_in,
                              void* d_out, int out_size, void* d_ws, size_t ws_size,
                              hipStream_t stream)
{
  const float* x     = (const float*)d_in[0];
  const float* eWih0 = (const float*)d_in[1];
  const float* eWhh0 = (const float*)d_in[2];
  const float* ebih0 = (const float*)d_in[3];
  const float* ebhh0 = (const float*)d_in[4];
  const float* eWih1 = (const float*)d_in[5];
  const float* eWhh1 = (const float*)d_in[6];
  const float* ebih1 = (const float*)d_in[7];
  const float* ebhh1 = (const float*)d_in[8];
  const float* bnW   = (const float*)d_in[9];
  const float* bnB   = (const float*)d_in[10];
  const float* exW   = (const float*)d_in[11];
  const float* exB   = (const float*)d_in[12];
  const float* dWih0 = (const float*)d_in[13];
  const float* dWhh0 = (const float*)d_in[14];
  const float* dbih0 = (const float*)d_in[15];
  const float* dbhh0 = (const float*)d_in[16];
  const float* dWih1 = (const float*)d_in[17];
  const float* dWhh1 = (const float*)d_in[18];
  const float* dbih1 = (const float*)d_in[19];
  const float* dbhh1 = (const float*)d_in[20];
  const float* outW  = (const float*)d_in[21];
  const float* outB  = (const float*)d_in[22];

  dim3 grid(BATCH / 64), block(256);
  hipLaunchKernelGGL(lstm_ae_mfma, grid, block, 0, stream,
                     x,
                     eWih0, eWhh0, ebih0, ebhh0,
                     eWih1, eWhh1, ebih1, ebhh1,
                     bnW, bnB, exW, exB,
                     dWih0, dWhh0, dbih0, dbhh0,
                     dWih1, dWhh1, dbih1, dbhh1,
                     outW, outB,
                     (float*)d_out);
}